// Round 23
// baseline (188.988 us; speedup 1.0000x reference)
//
#include <hip/hip_runtime.h>

typedef unsigned short u16;
typedef __attribute__((ext_vector_type(8))) short bf16x8;
typedef __attribute__((ext_vector_type(4))) float f32x4;
typedef __attribute__((ext_vector_type(16))) float f32x16;

#define LOG2E 1.44269504088896f

__device__ inline u16 f2b(float f) {
  union { float f; unsigned u; } x; x.f = f;
  unsigned r = x.u + 0x7fffu + ((x.u >> 16) & 1u);
  return (u16)(r >> 16);
}

__device__ inline void gload_lds16(const void* g, void* l) {
  __builtin_amdgcn_global_load_lds(
      (__attribute__((address_space(1))) void*)(g),
      (__attribute__((address_space(3))) void*)(l), 16, 0, 0);
}

__device__ inline unsigned cvtpk_bf16(float lo, float hi_) {
  unsigned r;
  asm("v_cvt_pk_bf16_f32 %0, %1, %2" : "=v"(r) : "v"(lo), "v"(hi_));
  return r;
}
// exp2 via builtin: emits v_exp_f32 WITH required TRANS-pipe hazard nops.
__device__ inline float exp2_hw(float x) { return __builtin_amdgcn_exp2f(x); }

// ---------------- f32 -> bf16 convert, WEIGHTS ONLY (4 x 1M elements) ----------------
__global__ __launch_bounds__(256) void cvt_w(
    const float* __restrict__ wq, const float* __restrict__ wk,
    const float* __restrict__ wv, const float* __restrict__ wo,
    u16* __restrict__ wqb, u16* __restrict__ wkb,
    u16* __restrict__ wvb, u16* __restrict__ wob) {
  int b = blockIdx.x;
  const int w = b >> 10;
  b &= 1023;
  const float* in = (w == 0) ? wq : (w == 1) ? wk : (w == 2) ? wv : wo;
  u16* out = (w == 0) ? wqb : (w == 1) ? wkb : (w == 2) ? wvb : wob;
  const int i = b * 256 + threadIdx.x;
  const float4 v = ((const float4*)in)[i];
  union { u16 s[4]; uint2 u; } o;
  o.s[0] = f2b(v.x); o.s[1] = f2b(v.y); o.s[2] = f2b(v.z); o.s[3] = f2b(v.w);
  ((uint2*)out)[i] = o.u;
}

// ---------------- O-GEMM (round-22 proven: BK=64, XOR-swizzled LDS) ----------------
__global__ __launch_bounds__(256) void gemm_o(
    const u16* __restrict__ A, const u16* __restrict__ W,
    const float* __restrict__ bias, float* __restrict__ Cout,
    int K) {
  __shared__ __align__(16) u16 lA[2][128 * 64];
  __shared__ __align__(16) u16 lW[2][128 * 64];
  const int tid = threadIdx.x, lane = tid & 63, wid = tid >> 6;
  const int wr = wid >> 1, wc = wid & 1;
  const int fr = lane & 15, fq = lane >> 4;
  const size_t abase = (size_t)blockIdx.x * 128 * K;
  const size_t wbase = (size_t)blockIdx.y * 128 * K;

  f32x4 acc[4][4];
#pragma unroll
  for (int i = 0; i < 4; ++i)
#pragma unroll
    for (int j = 0; j < 4; ++j) acc[i][j] = (f32x4){0.f, 0.f, 0.f, 0.f};

#define GSTAGE(bufi, kt)                                                          \
  do {                                                                            \
    _Pragma("unroll")                                                             \
    for (int is = 0; is < 4; ++is) {                                              \
      const int c = is * 256 + tid;                                               \
      const int r = c >> 3, ch = (c & 7) ^ (r & 7);                               \
      gload_lds16(A + abase + (size_t)r * K + (kt) + ch * 8, lA[bufi] + c * 8);   \
      gload_lds16(W + wbase + (size_t)r * K + (kt) + ch * 8, lW[bufi] + c * 8);   \
    }                                                                             \
  } while (0)

  GSTAGE(0, 0);
  __syncthreads();

  int buf = 0;
  for (int kt = 0; kt < K; kt += 64) {
    if (kt + 64 < K) GSTAGE(buf ^ 1, kt + 64);
#pragma unroll
    for (int kk = 0; kk < 2; ++kk) {
      bf16x8 af[4], wf[4];
#pragma unroll
      for (int m = 0; m < 4; ++m) {
        const int row = wr * 64 + m * 16 + fr;
        af[m] = *(const bf16x8*)&lA[buf][row * 64 + (((kk * 4 + fq) ^ (row & 7)) << 3)];
      }
#pragma unroll
      for (int n = 0; n < 4; ++n) {
        const int row = wc * 64 + n * 16 + fr;
        wf[n] = *(const bf16x8*)&lW[buf][row * 64 + (((kk * 4 + fq) ^ (row & 7)) << 3)];
      }
#pragma unroll
      for (int m = 0; m < 4; ++m)
#pragma unroll
        for (int n = 0; n < 4; ++n)
          acc[m][n] = __builtin_amdgcn_mfma_f32_16x16x32_bf16(af[m], wf[n], acc[m][n], 0, 0, 0);
    }
    __syncthreads();
    buf ^= 1;
  }
#undef GSTAGE

  const int row0 = blockIdx.x * 128 + wr * 64 + fq * 4;
  const int col0 = blockIdx.y * 128 + wc * 64 + fr;
#pragma unroll
  for (int n = 0; n < 4; ++n) {
    const int col = col0 + n * 16;
    const float bb = bias[col];
#pragma unroll
    for (int m = 0; m < 4; ++m) {
#pragma unroll
      for (int r = 0; r < 4; ++r) {
        const int row = row0 + m * 16 + r;
        Cout[(size_t)row * 1024 + col] = acc[m][n][r] + bb;
      }
    }
  }
}

// ---------------- fused Q+K+V GEMM with in-kernel activation cvt ----------------
// grid (64,24): y<8 -> Q (alpha folded, from f32 query); 8<=y<16 -> K; y>=16 -> V
// (fused Vt2-permute epilogue). A is reg-staged from f32 (T14: loads issued at
// loop top for t+1, cvt_pk + ds_write after compute, before the single barrier —
// same sync skeleton). W stays async gload_lds (bf16). LDS layout + XOR swizzle
// identical to round 22 (write chunk = r*8 + (gch^(r&7)) matches the read XOR).
__global__ __launch_bounds__(256) void gemm_qkv(
    const float* __restrict__ qA32, const float* __restrict__ kA32,
    const u16* __restrict__ Wq, const u16* __restrict__ Wk,
    const u16* __restrict__ Wv, const float* __restrict__ bq,
    const float* __restrict__ bk, const float* __restrict__ bv,
    u16* __restrict__ Qout, u16* __restrict__ Kout,
    u16* __restrict__ Vtout, int K) {
  __shared__ __align__(16) u16 lA[2][128 * 64];
  __shared__ __align__(16) u16 lW[2][128 * 64];
  const int tid = threadIdx.x, lane = tid & 63, wid = tid >> 6;
  const int wr = wid >> 1, wc = wid & 1;
  const int fr = lane & 15, fq = lane >> 4;
  const int path = blockIdx.y >> 3, ny = blockIdx.y & 7;
  const float* A32 = (path == 0) ? qA32 : kA32;
  const u16* W = (path == 0) ? Wq : (path == 1) ? Wk : Wv;
  const float* bias = (path == 0) ? bq : (path == 1) ? bk : bv;
  const size_t abase = (size_t)blockIdx.x * 128 * K;
  const size_t wbase = (size_t)ny * 128 * K;

  f32x4 acc[4][4];
#pragma unroll
  for (int i = 0; i < 4; ++i)
#pragma unroll
    for (int j = 0; j < 4; ++j) acc[i][j] = (f32x4){0.f, 0.f, 0.f, 0.f};

  // A staging: pair p = is*256+tid (is 0..3): row r=p>>3, global chunk gch=p&7
  // (8 bf16 = 2 float4). Loads coalesce (16 lanes cover a row's 8 chunk-pairs).
  float4 areg[8];

#define ALOAD(kt)                                                                  \
  do {                                                                             \
    _Pragma("unroll")                                                              \
    for (int is = 0; is < 4; ++is) {                                               \
      const int p = is * 256 + tid;                                                \
      const int r = p >> 3, gch = p & 7;                                           \
      const float* src = A32 + abase + (size_t)r * K + (kt) + gch * 8;             \
      areg[2 * is] = ((const float4*)src)[0];                                      \
      areg[2 * is + 1] = ((const float4*)src)[1];                                  \
    }                                                                              \
  } while (0)

#define AWRITE(bufi)                                                               \
  do {                                                                             \
    _Pragma("unroll")                                                              \
    for (int is = 0; is < 4; ++is) {                                               \
      const int p = is * 256 + tid;                                                \
      const int r = p >> 3, gch = p & 7;                                           \
      union { unsigned u[4]; uint4 v; } pk;                                        \
      pk.u[0] = cvtpk_bf16(areg[2 * is].x, areg[2 * is].y);                        \
      pk.u[1] = cvtpk_bf16(areg[2 * is].z, areg[2 * is].w);                        \
      pk.u[2] = cvtpk_bf16(areg[2 * is + 1].x, areg[2 * is + 1].y);                \
      pk.u[3] = cvtpk_bf16(areg[2 * is + 1].z, areg[2 * is + 1].w);                \
      *(uint4*)&lA[bufi][(r * 8 + (gch ^ (r & 7))) * 8] = pk.v;                    \
    }                                                                              \
  } while (0)

#define WSTAGE(bufi, kt)                                                           \
  do {                                                                             \
    _Pragma("unroll")                                                              \
    for (int is = 0; is < 4; ++is) {                                               \
      const int c = is * 256 + tid;                                                \
      const int r = c >> 3, ch = (c & 7) ^ (r & 7);                                \
      gload_lds16(W + wbase + (size_t)r * K + (kt) + ch * 8, lW[bufi] + c * 8);    \
    }                                                                              \
  } while (0)

  // prologue: tile 0 (A load latency exposed once)
  ALOAD(0);
  WSTAGE(0, 0);
  AWRITE(0);
  __syncthreads();

  int buf = 0;
  for (int kt = 0; kt < K; kt += 64) {
    if (kt + 64 < K) {
      ALOAD(kt + 64);       // issue f32 loads now; consumed after compute
      WSTAGE(buf ^ 1, kt + 64);
    }
#pragma unroll
    for (int kk = 0; kk < 2; ++kk) {
      bf16x8 af[4], wf[4];
#pragma unroll
      for (int m = 0; m < 4; ++m) {
        const int row = wr * 64 + m * 16 + fr;
        af[m] = *(const bf16x8*)&lA[buf][row * 64 + (((kk * 4 + fq) ^ (row & 7)) << 3)];
      }
#pragma unroll
      for (int n = 0; n < 4; ++n) {
        const int row = wc * 64 + n * 16 + fr;
        wf[n] = *(const bf16x8*)&lW[buf][row * 64 + (((kk * 4 + fq) ^ (row & 7)) << 3)];
      }
#pragma unroll
      for (int m = 0; m < 4; ++m)
#pragma unroll
        for (int n = 0; n < 4; ++n)
          acc[m][n] = __builtin_amdgcn_mfma_f32_16x16x32_bf16(af[m], wf[n], acc[m][n], 0, 0, 0);
    }
    if (kt + 64 < K) AWRITE(buf ^ 1);  // cvt + write into the other buffer
    __syncthreads();
    buf ^= 1;
  }
#undef ALOAD
#undef AWRITE
#undef WSTAGE

  if (path == 2) {
    // fused V epilogue: write bf16 directly in Vt2-permuted layout
    const int bI = blockIdx.x >> 4;
    const int srow0 = ((blockIdx.x * 128) & 2047) + wr * 64 + fq * 4;
    const int col0 = ny * 128 + wc * 64 + fr;
#pragma unroll
    for (int n = 0; n < 4; ++n) {
      const int col = col0 + n * 16;
      const float bb = bias[col];
      const int h = col >> 6, dl = col & 63;
      u16* vrow = Vtout + ((size_t)((bI * 16 + h) * 64 + dl)) * 2048;
#pragma unroll
      for (int m = 0; m < 4; ++m) {
        const int s = srow0 + m * 16;
        const int x = s & 15;
        const int pos = (((s & 63) >> 4) * 2 + ((x >> 2) & 1)) * 8 + ((x & 3) | ((x & 8) >> 1));
        union { u16 s4[4]; uint2 u; } w;
#pragma unroll
        for (int r = 0; r < 4; ++r) w.s4[r] = f2b(acc[m][n][r] + bb);
        *(uint2*)&vrow[(s >> 6) * 64 + pos] = w.u;
      }
    }
  } else {
    const float alpha = (path == 0) ? 0.125f * LOG2E : 1.0f;
    u16* Cout = (path == 0) ? Qout : Kout;
    const int row0 = blockIdx.x * 128 + wr * 64 + fq * 4;
    const int col0 = ny * 128 + wc * 64 + fr;
#pragma unroll
    for (int n = 0; n < 4; ++n) {
      const int col = col0 + n * 16;
      const float bb = bias[col];
#pragma unroll
      for (int m = 0; m < 4; ++m) {
#pragma unroll
        for (int r = 0; r < 4; ++r) {
          const int row = row0 + m * 16 + r;
          Cout[(size_t)row * 1024 + col] = f2b((acc[m][n][r] + bb) * alpha);
        }
      }
    }
  }
}

// ---------------- flash attention fwd (v16: unchanged from round 18) ----------------
__global__ __launch_bounds__(512, 4) void flash16(
    const u16* __restrict__ Qb, const u16* __restrict__ Kb,
    const u16* __restrict__ Vt, const float* __restrict__ mask,
    u16* __restrict__ Ob) {
  __shared__ __align__(16) u16 Kl[2][4096];
  __shared__ __align__(16) u16 Vl[2][4096];
  __shared__ unsigned long long bml[32];
  __shared__ float lbuf[8][32];

  const int f = blockIdx.x;
  const int xcd = f & 7, i = f >> 3;
  const int bh = xcd * 8 + (i >> 3);
  const int qt = i & 7;
  const int b = bh >> 4, h = bh & 15;
  const int tid = threadIdx.x, lane = tid & 63, wid = tid >> 6;
  const int l31 = lane & 31, hi = lane >> 5;
  const int qrow0 = qt * 256 + wid * 32;

  bf16x8 qf[4];
  {
    const u16* qp = Qb + ((size_t)(b * 2048 + qrow0 + l31)) * 1024 + h * 64;
#pragma unroll
    for (int dc = 0; dc < 4; ++dc) qf[dc] = *(const bf16x8*)(qp + dc * 16 + hi * 8);
  }

  const u16* kbase = Kb + ((size_t)(b * 2048)) * 1024 + h * 64;
  const u16* vbase = Vt + ((size_t)(bh * 64)) * 2048;
  const float* mrow = mask + b * 2048;

  const int l31s = tid & 31, his = (tid >> 5) & 1, mid = (tid >> 6) & 3,
            top = (tid >> 8) & 1;
  const int koff = (top * 32 + l31s) * 1024 + (mid * 2 + his) * 8;
  const int voff = (top * 32 + l31s) * 2048 + (mid * 2 + his) * 8;

  f32x16 o0 = {}, o1 = {};
  float l_r = 0.f;

#define STAGE(bufi, tt)                               \
  do {                                                \
    const u16* kb_t = kbase + (size_t)(tt) * 65536;   \
    const u16* vb_t = vbase + (tt) * 64;              \
    gload_lds16(kb_t + koff, &Kl[bufi][tid * 8]);     \
    gload_lds16(vb_t + voff, &Vl[bufi][tid * 8]);     \
  } while (0)

  STAGE(0, 0);

#pragma unroll
  for (int tt = 0; tt < 4; ++tt) {
    const int tile = wid * 4 + tt;
    const unsigned long long bmv = __ballot(mrow[tile * 64 + lane] == 1.0f);
    if (lane == 0) bml[tile] = bmv;
  }
  __syncthreads();

  const unsigned mflags =
      (unsigned)__ballot(lane < 32 && bml[lane] != ~0ull);

  for (int t = 0; t < 32; ++t) {
    const int cur = t & 1;
    if (t + 1 < 32) STAGE(cur ^ 1, t + 1);

    const u16* Kc = Kl[cur];
    const u16* Vc = Vl[cur];

#pragma unroll
    for (int n = 0; n < 2; ++n) {
      f32x16 acc = {};
#pragma unroll
      for (int dc = 0; dc < 4; ++dc) {
        const bf16x8 kf = *(const bf16x8*)&Kc[(n * 4 + dc) * 512 + lane * 8];
        acc = __builtin_amdgcn_mfma_f32_32x32x16_bf16(kf, qf[dc], acc, 0, 0, 0);
      }

#pragma unroll
      for (int reg = 0; reg < 16; ++reg) acc[reg] = exp2_hw(acc[reg]);

      if (mflags & (1u << t)) {
        const unsigned long long bm = bml[t];
#pragma unroll
        for (int reg = 0; reg < 16; ++reg) {
          const int k = n * 32 + (reg & 3) + 8 * (reg >> 2) + 4 * hi;
          if (!((bm >> k) & 1)) acc[reg] = 0.f;
        }
      }

      {
        float s0a = (acc[0] + acc[1]) + (acc[2] + acc[3]);
        float s1a = (acc[4] + acc[5]) + (acc[6] + acc[7]);
        float s2a = (acc[8] + acc[9]) + (acc[10] + acc[11]);
        float s3a = (acc[12] + acc[13]) + (acc[14] + acc[15]);
        l_r += (s0a + s1a) + (s2a + s3a);
      }

      bf16x8 pa0, pa1;
      {
        union { unsigned u[4]; bf16x8 v; } pk;
#pragma unroll
        for (int j = 0; j < 4; ++j) pk.u[j] = cvtpk_bf16(acc[2 * j], acc[2 * j + 1]);
        pa0 = pk.v;
#pragma unroll
        for (int j = 0; j < 4; ++j) pk.u[j] = cvtpk_bf16(acc[8 + 2 * j], acc[9 + 2 * j]);
        pa1 = pk.v;
      }

      {
        const bf16x8 v00 = *(const bf16x8*)&Vc[(0 * 4 + n * 2 + 0) * 512 + lane * 8];
        const bf16x8 v01 = *(const bf16x8*)&Vc[(0 * 4 + n * 2 + 1) * 512 + lane * 8];
        o0 = __builtin_amdgcn_mfma_f32_32x32x16_bf16(pa0, v00, o0, 0, 0, 0);
        o0 = __builtin_amdgcn_mfma_f32_32x32x16_bf16(pa1, v01, o0, 0, 0, 0);
      }
      {
        const bf16x8 v10 = *(const bf16x8*)&Vc[(1 * 4 + n * 2 + 0) * 512 + lane * 8];
        const bf16x8 v11 = *(const bf16x8*)&Vc[(1 * 4 + n * 2 + 1) * 512 + lane * 8];
        o1 = __builtin_amdgcn_mfma_f32_32x32x16_bf16(pa0, v10, o1, 0, 0, 0);
        o1 = __builtin_amdgcn_mfma_f32_32x32x16_bf16(pa1, v11, o1, 0, 0, 0);
      }
    }

    __syncthreads();
  }
#undef STAGE

  const float l_tot = l_r + __shfl_xor(l_r, 32);
  const float linv = 1.0f / l_tot;
  if (!hi) lbuf[wid][l31] = linv;
  __builtin_amdgcn_wave_barrier();
  float lv[16];
#pragma unroll
  for (int reg = 0; reg < 16; ++reg)
    lv[reg] = lbuf[wid][(reg & 3) + 8 * (reg >> 2) + 4 * hi];

  u16* ob = Ob + ((size_t)(b * 2048 + qrow0)) * 1024 + h * 64 + l31;
#pragma unroll
  for (int reg = 0; reg < 16; ++reg) {
    const int q = (reg & 3) + 8 * (reg >> 2) + 4 * hi;
    ob[(size_t)q * 1024] = f2b(o0[reg] * lv[reg]);
    ob[(size_t)q * 1024 + 32] = f2b(o1[reg] * lv[reg]);
  }
}

// ---------------- launch ----------------
extern "C" void kernel_launch(void* const* d_in, const int* in_sizes, int n_in,
                              void* d_out, int out_size, void* d_ws, size_t ws_size,
                              hipStream_t stream) {
  const float* query = (const float*)d_in[0];
  const float* keyin = (const float*)d_in[1];
  const float* maskp = (const float*)d_in[2];
  const float* Wq = (const float*)d_in[3];
  const float* bq = (const float*)d_in[4];
  const float* Wk = (const float*)d_in[5];
  const float* bk = (const float*)d_in[6];
  const float* Wv = (const float*)d_in[7];
  const float* bv = (const float*)d_in[8];
  const float* Wo = (const float*)d_in[9];
  const float* bo = (const float*)d_in[10];

  char* ws = (char*)d_ws;
  const size_t ACT = (size_t)8192 * 1024 * 2;   // 16 MB per bf16 activation buffer
  const size_t WMAT = (size_t)1024 * 1024 * 2;  // 2 MB per bf16 weight
  u16* wqb = (u16*)(ws + 2 * ACT);
  u16* wkb = (u16*)(ws + 2 * ACT + WMAT);
  u16* wvb = (u16*)(ws + 2 * ACT + 2 * WMAT);
  u16* wob = (u16*)(ws + 2 * ACT + 3 * WMAT);
  u16* Qb  = (u16*)(ws + 2 * ACT + 4 * WMAT);
  u16* Kb  = (u16*)(ws + 3 * ACT + 4 * WMAT);
  u16* VtDed = (u16*)(ws + 4 * ACT + 4 * WMAT);  // dedicated Vt2 region
  u16* attnb = (u16*)(ws + ACT);                 // scratch (was kbf region)

  cvt_w<<<4096, 256, 0, stream>>>(Wq, Wk, Wv, Wo, wqb, wkb, wvb, wob);

  // activations converted in-kernel (reg-staged f32 -> cvt_pk -> LDS)
  gemm_qkv<<<dim3(64, 24), 256, 0, stream>>>(query, keyin, wqb, wkb, wvb,
                                             bq, bk, bv, Qb, Kb, VtDed, 1024);

  flash16<<<512, 512, 0, stream>>>(Qb, Kb, VtDed, maskp, attnb);

  gemm_o<<<dim3(64, 8), 256, 0, stream>>>(attnb, wob, bo, (float*)d_out, 1024);
}

// Round 24
// 184.735 us; speedup vs baseline: 1.0230x; 1.0230x over previous
//
#include <hip/hip_runtime.h>

typedef unsigned short u16;
typedef __attribute__((ext_vector_type(8))) short bf16x8;
typedef __attribute__((ext_vector_type(4))) float f32x4;
typedef __attribute__((ext_vector_type(16))) float f32x16;

#define LOG2E 1.44269504088896f

__device__ inline u16 f2b(float f) {
  union { float f; unsigned u; } x; x.f = f;
  unsigned r = x.u + 0x7fffu + ((x.u >> 16) & 1u);
  return (u16)(r >> 16);
}

__device__ inline void gload_lds16(const void* g, void* l) {
  __builtin_amdgcn_global_load_lds(
      (__attribute__((address_space(1))) void*)(g),
      (__attribute__((address_space(3))) void*)(l), 16, 0, 0);
}

__device__ inline unsigned cvtpk_bf16(float lo, float hi_) {
  unsigned r;
  asm("v_cvt_pk_bf16_f32 %0, %1, %2" : "=v"(r) : "v"(lo), "v"(hi_));
  return r;
}
// exp2 via builtin: emits v_exp_f32 WITH required TRANS-pipe hazard nops.
__device__ inline float exp2_hw(float x) { return __builtin_amdgcn_exp2f(x); }

// ---------------- fused f32 -> bf16 convert (all 6 tensors, one launch) ----------------
__global__ __launch_bounds__(256) void cvt_all(
    const float* __restrict__ q, const float* __restrict__ k,
    const float* __restrict__ wq, const float* __restrict__ wk,
    const float* __restrict__ wv, const float* __restrict__ wo,
    u16* __restrict__ qb, u16* __restrict__ kb,
    u16* __restrict__ wqb, u16* __restrict__ wkb,
    u16* __restrict__ wvb, u16* __restrict__ wob) {
  int b = blockIdx.x;
  const float* in;
  u16* out;
  if (b < 8192) {
    in = q; out = qb;
  } else if (b < 16384) {
    in = k; out = kb; b -= 8192;
  } else {
    const int w = (b - 16384) >> 10;
    b = (b - 16384) & 1023;
    in = (w == 0) ? wq : (w == 1) ? wk : (w == 2) ? wv : wo;
    out = (w == 0) ? wqb : (w == 1) ? wkb : (w == 2) ? wvb : wob;
  }
  const int i = b * 256 + threadIdx.x;
  const float4 v = ((const float4*)in)[i];
  union { u16 s[4]; uint2 u; } o;
  o.s[0] = f2b(v.x); o.s[1] = f2b(v.y); o.s[2] = f2b(v.z); o.s[3] = f2b(v.w);
  ((uint2*)out)[i] = o.u;
}

// ---- BK=64 GEMM with XOR-swizzled LDS (round-22 proven: linear LDS dest,
// pre-swizzled global source chunk ch=(c&7)^(r&7), same XOR on read).

// ---------------- O-GEMM ----------------
__global__ __launch_bounds__(256) void gemm_o(
    const u16* __restrict__ A, const u16* __restrict__ W,
    const float* __restrict__ bias, float* __restrict__ Cout,
    int K) {
  __shared__ __align__(16) u16 lA[2][128 * 64];
  __shared__ __align__(16) u16 lW[2][128 * 64];
  const int tid = threadIdx.x, lane = tid & 63, wid = tid >> 6;
  const int wr = wid >> 1, wc = wid & 1;
  const int fr = lane & 15, fq = lane >> 4;
  const size_t abase = (size_t)blockIdx.x * 128 * K;
  const size_t wbase = (size_t)blockIdx.y * 128 * K;

  f32x4 acc[4][4];
#pragma unroll
  for (int i = 0; i < 4; ++i)
#pragma unroll
    for (int j = 0; j < 4; ++j) acc[i][j] = (f32x4){0.f, 0.f, 0.f, 0.f};

#define GSTAGE(bufi, kt)                                                          \
  do {                                                                            \
    _Pragma("unroll")                                                             \
    for (int is = 0; is < 4; ++is) {                                              \
      const int c = is * 256 + tid;                                               \
      const int r = c >> 3, ch = (c & 7) ^ (r & 7);                               \
      gload_lds16(A + abase + (size_t)r * K + (kt) + ch * 8, lA[bufi] + c * 8);   \
      gload_lds16(W + wbase + (size_t)r * K + (kt) + ch * 8, lW[bufi] + c * 8);   \
    }                                                                             \
  } while (0)

  GSTAGE(0, 0);
  __syncthreads();

  int buf = 0;
  for (int kt = 0; kt < K; kt += 64) {
    if (kt + 64 < K) GSTAGE(buf ^ 1, kt + 64);
#pragma unroll
    for (int kk = 0; kk < 2; ++kk) {
      bf16x8 af[4], wf[4];
#pragma unroll
      for (int m = 0; m < 4; ++m) {
        const int row = wr * 64 + m * 16 + fr;
        af[m] = *(const bf16x8*)&lA[buf][row * 64 + (((kk * 4 + fq) ^ (row & 7)) << 3)];
      }
#pragma unroll
      for (int n = 0; n < 4; ++n) {
        const int row = wc * 64 + n * 16 + fr;
        wf[n] = *(const bf16x8*)&lW[buf][row * 64 + (((kk * 4 + fq) ^ (row & 7)) << 3)];
      }
#pragma unroll
      for (int m = 0; m < 4; ++m)
#pragma unroll
        for (int n = 0; n < 4; ++n)
          acc[m][n] = __builtin_amdgcn_mfma_f32_16x16x32_bf16(af[m], wf[n], acc[m][n], 0, 0, 0);
    }
    __syncthreads();
    buf ^= 1;
  }
#undef GSTAGE

  const int row0 = blockIdx.x * 128 + wr * 64 + fq * 4;
  const int col0 = blockIdx.y * 128 + wc * 64 + fr;
#pragma unroll
  for (int n = 0; n < 4; ++n) {
    const int col = col0 + n * 16;
    const float bb = bias[col];
#pragma unroll
    for (int m = 0; m < 4; ++m) {
#pragma unroll
      for (int r = 0; r < 4; ++r) {
        const int row = row0 + m * 16 + r;
        Cout[(size_t)row * 1024 + col] = acc[m][n][r] + bb;
      }
    }
  }
}

// ---------------- fused Q+K+V GEMM ----------------
// grid (64,24): y<8 -> Q (alpha=0.125*LOG2E, from qA); 8<=y<16 -> K (from kA);
// y>=16 -> V (from kA, fused Vt2-permute epilogue).
__global__ __launch_bounds__(256) void gemm_qkv(
    const u16* __restrict__ qA, const u16* __restrict__ kA,
    const u16* __restrict__ Wq, const u16* __restrict__ Wk,
    const u16* __restrict__ Wv, const float* __restrict__ bq,
    const float* __restrict__ bk, const float* __restrict__ bv,
    u16* __restrict__ Qout, u16* __restrict__ Kout,
    u16* __restrict__ Vtout, int K) {
  __shared__ __align__(16) u16 lA[2][128 * 64];
  __shared__ __align__(16) u16 lW[2][128 * 64];
  const int tid = threadIdx.x, lane = tid & 63, wid = tid >> 6;
  const int wr = wid >> 1, wc = wid & 1;
  const int fr = lane & 15, fq = lane >> 4;
  const int path = blockIdx.y >> 3, ny = blockIdx.y & 7;
  const u16* A = (path == 0) ? qA : kA;
  const u16* W = (path == 0) ? Wq : (path == 1) ? Wk : Wv;
  const float* bias = (path == 0) ? bq : (path == 1) ? bk : bv;
  const size_t abase = (size_t)blockIdx.x * 128 * K;
  const size_t wbase = (size_t)ny * 128 * K;

  f32x4 acc[4][4];
#pragma unroll
  for (int i = 0; i < 4; ++i)
#pragma unroll
    for (int j = 0; j < 4; ++j) acc[i][j] = (f32x4){0.f, 0.f, 0.f, 0.f};

#define GSTAGE(bufi, kt)                                                          \
  do {                                                                            \
    _Pragma("unroll")                                                             \
    for (int is = 0; is < 4; ++is) {                                              \
      const int c = is * 256 + tid;                                               \
      const int r = c >> 3, ch = (c & 7) ^ (r & 7);                               \
      gload_lds16(A + abase + (size_t)r * K + (kt) + ch * 8, lA[bufi] + c * 8);   \
      gload_lds16(W + wbase + (size_t)r * K + (kt) + ch * 8, lW[bufi] + c * 8);   \
    }                                                                             \
  } while (0)

  GSTAGE(0, 0);
  __syncthreads();

  int buf = 0;
  for (int kt = 0; kt < K; kt += 64) {
    if (kt + 64 < K) GSTAGE(buf ^ 1, kt + 64);
#pragma unroll
    for (int kk = 0; kk < 2; ++kk) {
      bf16x8 af[4], wf[4];
#pragma unroll
      for (int m = 0; m < 4; ++m) {
        const int row = wr * 64 + m * 16 + fr;
        af[m] = *(const bf16x8*)&lA[buf][row * 64 + (((kk * 4 + fq) ^ (row & 7)) << 3)];
      }
#pragma unroll
      for (int n = 0; n < 4; ++n) {
        const int row = wc * 64 + n * 16 + fr;
        wf[n] = *(const bf16x8*)&lW[buf][row * 64 + (((kk * 4 + fq) ^ (row & 7)) << 3)];
      }
#pragma unroll
      for (int m = 0; m < 4; ++m)
#pragma unroll
        for (int n = 0; n < 4; ++n)
          acc[m][n] = __builtin_amdgcn_mfma_f32_16x16x32_bf16(af[m], wf[n], acc[m][n], 0, 0, 0);
    }
    __syncthreads();
    buf ^= 1;
  }
#undef GSTAGE

  if (path == 2) {
    // fused V epilogue: write bf16 directly in Vt2-permuted layout
    const int bI = blockIdx.x >> 4;
    const int srow0 = ((blockIdx.x * 128) & 2047) + wr * 64 + fq * 4;
    const int col0 = ny * 128 + wc * 64 + fr;
#pragma unroll
    for (int n = 0; n < 4; ++n) {
      const int col = col0 + n * 16;
      const float bb = bias[col];
      const int h = col >> 6, dl = col & 63;
      u16* vrow = Vtout + ((size_t)((bI * 16 + h) * 64 + dl)) * 2048;
#pragma unroll
      for (int m = 0; m < 4; ++m) {
        const int s = srow0 + m * 16;
        const int x = s & 15;
        const int pos = (((s & 63) >> 4) * 2 + ((x >> 2) & 1)) * 8 + ((x & 3) | ((x & 8) >> 1));
        union { u16 s4[4]; uint2 u; } w;
#pragma unroll
        for (int r = 0; r < 4; ++r) w.s4[r] = f2b(acc[m][n][r] + bb);
        *(uint2*)&vrow[(s >> 6) * 64 + pos] = w.u;
      }
    }
  } else {
    const float alpha = (path == 0) ? 0.125f * LOG2E : 1.0f;
    u16* Cout = (path == 0) ? Qout : Kout;
    const int row0 = blockIdx.x * 128 + wr * 64 + fq * 4;
    const int col0 = ny * 128 + wc * 64 + fr;
#pragma unroll
    for (int n = 0; n < 4; ++n) {
      const int col = col0 + n * 16;
      const float bb = bias[col];
#pragma unroll
      for (int m = 0; m < 4; ++m) {
#pragma unroll
        for (int r = 0; r < 4; ++r) {
          const int row = row0 + m * 16 + r;
          Cout[(size_t)row * 1024 + col] = f2b((acc[m][n][r] + bb) * alpha);
        }
      }
    }
  }
}

// ---------------- flash attention fwd (v17: v16 + T5 setprio around MFMA) ----------------
__global__ __launch_bounds__(512, 4) void flash17(
    const u16* __restrict__ Qb, const u16* __restrict__ Kb,
    const u16* __restrict__ Vt, const float* __restrict__ mask,
    u16* __restrict__ Ob) {
  __shared__ __align__(16) u16 Kl[2][4096];
  __shared__ __align__(16) u16 Vl[2][4096];
  __shared__ unsigned long long bml[32];
  __shared__ float lbuf[8][32];

  const int f = blockIdx.x;
  const int xcd = f & 7, i = f >> 3;
  const int bh = xcd * 8 + (i >> 3);
  const int qt = i & 7;
  const int b = bh >> 4, h = bh & 15;
  const int tid = threadIdx.x, lane = tid & 63, wid = tid >> 6;
  const int l31 = lane & 31, hi = lane >> 5;
  const int qrow0 = qt * 256 + wid * 32;

  bf16x8 qf[4];
  {
    const u16* qp = Qb + ((size_t)(b * 2048 + qrow0 + l31)) * 1024 + h * 64;
#pragma unroll
    for (int dc = 0; dc < 4; ++dc) qf[dc] = *(const bf16x8*)(qp + dc * 16 + hi * 8);
  }

  const u16* kbase = Kb + ((size_t)(b * 2048)) * 1024 + h * 64;
  const u16* vbase = Vt + ((size_t)(bh * 64)) * 2048;
  const float* mrow = mask + b * 2048;

  const int l31s = tid & 31, his = (tid >> 5) & 1, mid = (tid >> 6) & 3,
            top = (tid >> 8) & 1;
  const int koff = (top * 32 + l31s) * 1024 + (mid * 2 + his) * 8;
  const int voff = (top * 32 + l31s) * 2048 + (mid * 2 + his) * 8;

  f32x16 o0 = {}, o1 = {};
  float l_r = 0.f;

#define STAGE(bufi, tt)                               \
  do {                                                \
    const u16* kb_t = kbase + (size_t)(tt) * 65536;   \
    const u16* vb_t = vbase + (tt) * 64;              \
    gload_lds16(kb_t + koff, &Kl[bufi][tid * 8]);     \
    gload_lds16(vb_t + voff, &Vl[bufi][tid * 8]);     \
  } while (0)

  STAGE(0, 0);

#pragma unroll
  for (int tt = 0; tt < 4; ++tt) {
    const int tile = wid * 4 + tt;
    const unsigned long long bmv = __ballot(mrow[tile * 64 + lane] == 1.0f);
    if (lane == 0) bml[tile] = bmv;
  }
  __syncthreads();

  const unsigned mflags =
      (unsigned)__ballot(lane < 32 && bml[lane] != ~0ull);

  for (int t = 0; t < 32; ++t) {
    const int cur = t & 1;
    if (t + 1 < 32) STAGE(cur ^ 1, t + 1);

    const u16* Kc = Kl[cur];
    const u16* Vc = Vl[cur];

#pragma unroll
    for (int n = 0; n < 2; ++n) {
      f32x16 acc = {};
      __builtin_amdgcn_s_setprio(1);
#pragma unroll
      for (int dc = 0; dc < 4; ++dc) {
        const bf16x8 kf = *(const bf16x8*)&Kc[(n * 4 + dc) * 512 + lane * 8];
        acc = __builtin_amdgcn_mfma_f32_32x32x16_bf16(kf, qf[dc], acc, 0, 0, 0);
      }
      __builtin_amdgcn_s_setprio(0);

#pragma unroll
      for (int reg = 0; reg < 16; ++reg) acc[reg] = exp2_hw(acc[reg]);

      if (mflags & (1u << t)) {
        const unsigned long long bm = bml[t];
#pragma unroll
        for (int reg = 0; reg < 16; ++reg) {
          const int k = n * 32 + (reg & 3) + 8 * (reg >> 2) + 4 * hi;
          if (!((bm >> k) & 1)) acc[reg] = 0.f;
        }
      }

      {
        float s0a = (acc[0] + acc[1]) + (acc[2] + acc[3]);
        float s1a = (acc[4] + acc[5]) + (acc[6] + acc[7]);
        float s2a = (acc[8] + acc[9]) + (acc[10] + acc[11]);
        float s3a = (acc[12] + acc[13]) + (acc[14] + acc[15]);
        l_r += (s0a + s1a) + (s2a + s3a);
      }

      bf16x8 pa0, pa1;
      {
        union { unsigned u[4]; bf16x8 v; } pk;
#pragma unroll
        for (int j = 0; j < 4; ++j) pk.u[j] = cvtpk_bf16(acc[2 * j], acc[2 * j + 1]);
        pa0 = pk.v;
#pragma unroll
        for (int j = 0; j < 4; ++j) pk.u[j] = cvtpk_bf16(acc[8 + 2 * j], acc[9 + 2 * j]);
        pa1 = pk.v;
      }

      __builtin_amdgcn_s_setprio(1);
      {
        const bf16x8 v00 = *(const bf16x8*)&Vc[(0 * 4 + n * 2 + 0) * 512 + lane * 8];
        const bf16x8 v01 = *(const bf16x8*)&Vc[(0 * 4 + n * 2 + 1) * 512 + lane * 8];
        o0 = __builtin_amdgcn_mfma_f32_32x32x16_bf16(pa0, v00, o0, 0, 0, 0);
        o0 = __builtin_amdgcn_mfma_f32_32x32x16_bf16(pa1, v01, o0, 0, 0, 0);
      }
      {
        const bf16x8 v10 = *(const bf16x8*)&Vc[(1 * 4 + n * 2 + 0) * 512 + lane * 8];
        const bf16x8 v11 = *(const bf16x8*)&Vc[(1 * 4 + n * 2 + 1) * 512 + lane * 8];
        o1 = __builtin_amdgcn_mfma_f32_32x32x16_bf16(pa0, v10, o1, 0, 0, 0);
        o1 = __builtin_amdgcn_mfma_f32_32x32x16_bf16(pa1, v11, o1, 0, 0, 0);
      }
      __builtin_amdgcn_s_setprio(0);
    }

    __syncthreads();
  }
#undef STAGE

  const float l_tot = l_r + __shfl_xor(l_r, 32);
  const float linv = 1.0f / l_tot;
  if (!hi) lbuf[wid][l31] = linv;
  __builtin_amdgcn_wave_barrier();
  float lv[16];
#pragma unroll
  for (int reg = 0; reg < 16; ++reg)
    lv[reg] = lbuf[wid][(reg & 3) + 8 * (reg >> 2) + 4 * hi];

  u16* ob = Ob + ((size_t)(b * 2048 + qrow0)) * 1024 + h * 64 + l31;
#pragma unroll
  for (int reg = 0; reg < 16; ++reg) {
    const int q = (reg & 3) + 8 * (reg >> 2) + 4 * hi;
    ob[(size_t)q * 1024] = f2b(o0[reg] * lv[reg]);
    ob[(size_t)q * 1024 + 32] = f2b(o1[reg] * lv[reg]);
  }
}

// ---------------- launch ----------------
extern "C" void kernel_launch(void* const* d_in, const int* in_sizes, int n_in,
                              void* d_out, int out_size, void* d_ws, size_t ws_size,
                              hipStream_t stream) {
  const float* query = (const float*)d_in[0];
  const float* keyin = (const float*)d_in[1];
  const float* maskp = (const float*)d_in[2];
  const float* Wq = (const float*)d_in[3];
  const float* bq = (const float*)d_in[4];
  const float* Wk = (const float*)d_in[5];
  const float* bk = (const float*)d_in[6];
  const float* Wv = (const float*)d_in[7];
  const float* bv = (const float*)d_in[8];
  const float* Wo = (const float*)d_in[9];
  const float* bo = (const float*)d_in[10];

  char* ws = (char*)d_ws;
  const size_t ACT = (size_t)8192 * 1024 * 2;   // 16 MB per bf16 activation buffer
  const size_t WMAT = (size_t)1024 * 1024 * 2;  // 2 MB per bf16 weight
  u16* qbf = (u16*)(ws);
  u16* kbf = (u16*)(ws + ACT);                  // later reused as attn out
  u16* wqb = (u16*)(ws + 2 * ACT);
  u16* wkb = (u16*)(ws + 2 * ACT + WMAT);
  u16* wvb = (u16*)(ws + 2 * ACT + 2 * WMAT);
  u16* wob = (u16*)(ws + 2 * ACT + 3 * WMAT);
  u16* Qb  = (u16*)(ws + 2 * ACT + 4 * WMAT);
  u16* Kb  = (u16*)(ws + 3 * ACT + 4 * WMAT);
  u16* VtDed = (u16*)(ws + 4 * ACT + 4 * WMAT);  // dedicated Vt2 region
  u16* attnb = kbf;

  cvt_all<<<20480, 256, 0, stream>>>(query, keyin, Wq, Wk, Wv, Wo,
                                     qbf, kbf, wqb, wkb, wvb, wob);

  gemm_qkv<<<dim3(64, 24), 256, 0, stream>>>(qbf, kbf, wqb, wkb, wvb,
                                             bq, bk, bv, Qb, Kb, VtDed, 1024);

  flash17<<<512, 512, 0, stream>>>(Qb, Kb, VtDed, maskp, attnb);

  gemm_o<<<dim3(64, 8), 256, 0, stream>>>(attnb, wob, bo, (float*)d_out, 1024);
}

// Round 25
// 179.881 us; speedup vs baseline: 1.0506x; 1.0270x over previous
//
#include <hip/hip_runtime.h>

typedef unsigned short u16;
typedef __attribute__((ext_vector_type(8))) short bf16x8;
typedef __attribute__((ext_vector_type(4))) float f32x4;
typedef __attribute__((ext_vector_type(16))) float f32x16;

#define LOG2E 1.44269504088896f

__device__ inline u16 f2b(float f) {
  union { float f; unsigned u; } x; x.f = f;
  unsigned r = x.u + 0x7fffu + ((x.u >> 16) & 1u);
  return (u16)(r >> 16);
}

__device__ inline void gload_lds16(const void* g, void* l) {
  __builtin_amdgcn_global_load_lds(
      (__attribute__((address_space(1))) void*)(g),
      (__attribute__((address_space(3))) void*)(l), 16, 0, 0);
}

__device__ inline unsigned cvtpk_bf16(float lo, float hi_) {
  unsigned r;
  asm("v_cvt_pk_bf16_f32 %0, %1, %2" : "=v"(r) : "v"(lo), "v"(hi_));
  return r;
}
// exp2 via builtin: emits v_exp_f32 WITH required TRANS-pipe hazard nops.
__device__ inline float exp2_hw(float x) { return __builtin_amdgcn_exp2f(x); }

// ---------------- fused f32 -> bf16 convert (all 6 tensors, one launch) ----------------
__global__ __launch_bounds__(256) void cvt_all(
    const float* __restrict__ q, const float* __restrict__ k,
    const float* __restrict__ wq, const float* __restrict__ wk,
    const float* __restrict__ wv, const float* __restrict__ wo,
    u16* __restrict__ qb, u16* __restrict__ kb,
    u16* __restrict__ wqb, u16* __restrict__ wkb,
    u16* __restrict__ wvb, u16* __restrict__ wob) {
  int b = blockIdx.x;
  const float* in;
  u16* out;
  if (b < 8192) {
    in = q; out = qb;
  } else if (b < 16384) {
    in = k; out = kb; b -= 8192;
  } else {
    const int w = (b - 16384) >> 10;
    b = (b - 16384) & 1023;
    in = (w == 0) ? wq : (w == 1) ? wk : (w == 2) ? wv : wo;
    out = (w == 0) ? wqb : (w == 1) ? wkb : (w == 2) ? wvb : wob;
  }
  const int i = b * 256 + threadIdx.x;
  const float4 v = ((const float4*)in)[i];
  union { u16 s[4]; uint2 u; } o;
  o.s[0] = f2b(v.x); o.s[1] = f2b(v.y); o.s[2] = f2b(v.z); o.s[3] = f2b(v.w);
  ((uint2*)out)[i] = o.u;
}

// ---- BK=64 GEMM with XOR-swizzled LDS (round-22 proven: linear LDS dest,
// pre-swizzled global source chunk ch=(c&7)^(r&7), same XOR on read).

// ---------------- O-GEMM ----------------
__global__ __launch_bounds__(256) void gemm_o(
    const u16* __restrict__ A, const u16* __restrict__ W,
    const float* __restrict__ bias, float* __restrict__ Cout,
    int K) {
  __shared__ __align__(16) u16 lA[2][128 * 64];
  __shared__ __align__(16) u16 lW[2][128 * 64];
  const int tid = threadIdx.x, lane = tid & 63, wid = tid >> 6;
  const int wr = wid >> 1, wc = wid & 1;
  const int fr = lane & 15, fq = lane >> 4;
  const size_t abase = (size_t)blockIdx.x * 128 * K;
  const size_t wbase = (size_t)blockIdx.y * 128 * K;

  f32x4 acc[4][4];
#pragma unroll
  for (int i = 0; i < 4; ++i)
#pragma unroll
    for (int j = 0; j < 4; ++j) acc[i][j] = (f32x4){0.f, 0.f, 0.f, 0.f};

#define GSTAGE(bufi, kt)                                                          \
  do {                                                                            \
    _Pragma("unroll")                                                             \
    for (int is = 0; is < 4; ++is) {                                              \
      const int c = is * 256 + tid;                                               \
      const int r = c >> 3, ch = (c & 7) ^ (r & 7);                               \
      gload_lds16(A + abase + (size_t)r * K + (kt) + ch * 8, lA[bufi] + c * 8);   \
      gload_lds16(W + wbase + (size_t)r * K + (kt) + ch * 8, lW[bufi] + c * 8);   \
    }                                                                             \
  } while (0)

  GSTAGE(0, 0);
  __syncthreads();

  int buf = 0;
  for (int kt = 0; kt < K; kt += 64) {
    if (kt + 64 < K) GSTAGE(buf ^ 1, kt + 64);
#pragma unroll
    for (int kk = 0; kk < 2; ++kk) {
      bf16x8 af[4], wf[4];
#pragma unroll
      for (int m = 0; m < 4; ++m) {
        const int row = wr * 64 + m * 16 + fr;
        af[m] = *(const bf16x8*)&lA[buf][row * 64 + (((kk * 4 + fq) ^ (row & 7)) << 3)];
      }
#pragma unroll
      for (int n = 0; n < 4; ++n) {
        const int row = wc * 64 + n * 16 + fr;
        wf[n] = *(const bf16x8*)&lW[buf][row * 64 + (((kk * 4 + fq) ^ (row & 7)) << 3)];
      }
#pragma unroll
      for (int m = 0; m < 4; ++m)
#pragma unroll
        for (int n = 0; n < 4; ++n)
          acc[m][n] = __builtin_amdgcn_mfma_f32_16x16x32_bf16(af[m], wf[n], acc[m][n], 0, 0, 0);
    }
    __syncthreads();
    buf ^= 1;
  }
#undef GSTAGE

  const int row0 = blockIdx.x * 128 + wr * 64 + fq * 4;
  const int col0 = blockIdx.y * 128 + wc * 64 + fr;
#pragma unroll
  for (int n = 0; n < 4; ++n) {
    const int col = col0 + n * 16;
    const float bb = bias[col];
#pragma unroll
    for (int m = 0; m < 4; ++m) {
#pragma unroll
      for (int r = 0; r < 4; ++r) {
        const int row = row0 + m * 16 + r;
        Cout[(size_t)row * 1024 + col] = acc[m][n][r] + bb;
      }
    }
  }
}

// ---------------- fused Q+K+V GEMM ----------------
// grid (64,24): y<8 -> Q (alpha=0.125*LOG2E, from qA); 8<=y<16 -> K (from kA);
// y>=16 -> V (from kA, fused Vt2-permute epilogue).
__global__ __launch_bounds__(256) void gemm_qkv(
    const u16* __restrict__ qA, const u16* __restrict__ kA,
    const u16* __restrict__ Wq, const u16* __restrict__ Wk,
    const u16* __restrict__ Wv, const float* __restrict__ bq,
    const float* __restrict__ bk, const float* __restrict__ bv,
    u16* __restrict__ Qout, u16* __restrict__ Kout,
    u16* __restrict__ Vtout, int K) {
  __shared__ __align__(16) u16 lA[2][128 * 64];
  __shared__ __align__(16) u16 lW[2][128 * 64];
  const int tid = threadIdx.x, lane = tid & 63, wid = tid >> 6;
  const int wr = wid >> 1, wc = wid & 1;
  const int fr = lane & 15, fq = lane >> 4;
  const int path = blockIdx.y >> 3, ny = blockIdx.y & 7;
  const u16* A = (path == 0) ? qA : kA;
  const u16* W = (path == 0) ? Wq : (path == 1) ? Wk : Wv;
  const float* bias = (path == 0) ? bq : (path == 1) ? bk : bv;
  const size_t abase = (size_t)blockIdx.x * 128 * K;
  const size_t wbase = (size_t)ny * 128 * K;

  f32x4 acc[4][4];
#pragma unroll
  for (int i = 0; i < 4; ++i)
#pragma unroll
    for (int j = 0; j < 4; ++j) acc[i][j] = (f32x4){0.f, 0.f, 0.f, 0.f};

#define GSTAGE(bufi, kt)                                                          \
  do {                                                                            \
    _Pragma("unroll")                                                             \
    for (int is = 0; is < 4; ++is) {                                              \
      const int c = is * 256 + tid;                                               \
      const int r = c >> 3, ch = (c & 7) ^ (r & 7);                               \
      gload_lds16(A + abase + (size_t)r * K + (kt) + ch * 8, lA[bufi] + c * 8);   \
      gload_lds16(W + wbase + (size_t)r * K + (kt) + ch * 8, lW[bufi] + c * 8);   \
    }                                                                             \
  } while (0)

  GSTAGE(0, 0);
  __syncthreads();

  int buf = 0;
  for (int kt = 0; kt < K; kt += 64) {
    if (kt + 64 < K) GSTAGE(buf ^ 1, kt + 64);
#pragma unroll
    for (int kk = 0; kk < 2; ++kk) {
      bf16x8 af[4], wf[4];
#pragma unroll
      for (int m = 0; m < 4; ++m) {
        const int row = wr * 64 + m * 16 + fr;
        af[m] = *(const bf16x8*)&lA[buf][row * 64 + (((kk * 4 + fq) ^ (row & 7)) << 3)];
      }
#pragma unroll
      for (int n = 0; n < 4; ++n) {
        const int row = wc * 64 + n * 16 + fr;
        wf[n] = *(const bf16x8*)&lW[buf][row * 64 + (((kk * 4 + fq) ^ (row & 7)) << 3)];
      }
#pragma unroll
      for (int m = 0; m < 4; ++m)
#pragma unroll
        for (int n = 0; n < 4; ++n)
          acc[m][n] = __builtin_amdgcn_mfma_f32_16x16x32_bf16(af[m], wf[n], acc[m][n], 0, 0, 0);
    }
    __syncthreads();
    buf ^= 1;
  }
#undef GSTAGE

  if (path == 2) {
    // fused V epilogue: write bf16 directly in Vt2-permuted layout
    const int bI = blockIdx.x >> 4;
    const int srow0 = ((blockIdx.x * 128) & 2047) + wr * 64 + fq * 4;
    const int col0 = ny * 128 + wc * 64 + fr;
#pragma unroll
    for (int n = 0; n < 4; ++n) {
      const int col = col0 + n * 16;
      const float bb = bias[col];
      const int h = col >> 6, dl = col & 63;
      u16* vrow = Vtout + ((size_t)((bI * 16 + h) * 64 + dl)) * 2048;
#pragma unroll
      for (int m = 0; m < 4; ++m) {
        const int s = srow0 + m * 16;
        const int x = s & 15;
        const int pos = (((s & 63) >> 4) * 2 + ((x >> 2) & 1)) * 8 + ((x & 3) | ((x & 8) >> 1));
        union { u16 s4[4]; uint2 u; } w;
#pragma unroll
        for (int r = 0; r < 4; ++r) w.s4[r] = f2b(acc[m][n][r] + bb);
        *(uint2*)&vrow[(s >> 6) * 64 + pos] = w.u;
      }
    }
  } else {
    const float alpha = (path == 0) ? 0.125f * LOG2E : 1.0f;
    u16* Cout = (path == 0) ? Qout : Kout;
    const int row0 = blockIdx.x * 128 + wr * 64 + fq * 4;
    const int col0 = ny * 128 + wc * 64 + fr;
#pragma unroll
    for (int n = 0; n < 4; ++n) {
      const int col = col0 + n * 16;
      const float bb = bias[col];
#pragma unroll
      for (int m = 0; m < 4; ++m) {
#pragma unroll
        for (int r = 0; r < 4; ++r) {
          const int row = row0 + m * 16 + r;
          Cout[(size_t)row * 1024 + col] = f2b((acc[m][n][r] + bb) * alpha);
        }
      }
    }
  }
}

// ---------------- flash attention fwd (v18: flash16 body, relaxed reg bound) ----------------
// Grid is 512 blocks = exactly 2 blocks/CU (grid-limited residency). (512,4)
// forced a 128-unified ceiling -> 64 arch VGPRs -> ~52 MB scratch spill.
// (512,3) lets the allocator use its natural ~90-110 arch VGPRs (no spill);
// hardware still fits 4 waves/SIMD as long as unified usage <= 128/wave,
// so the 2-blocks/CU residency is unchanged.
__global__ __launch_bounds__(512, 3) void flash18(
    const u16* __restrict__ Qb, const u16* __restrict__ Kb,
    const u16* __restrict__ Vt, const float* __restrict__ mask,
    u16* __restrict__ Ob) {
  __shared__ __align__(16) u16 Kl[2][4096];
  __shared__ __align__(16) u16 Vl[2][4096];
  __shared__ unsigned long long bml[32];
  __shared__ float lbuf[8][32];

  const int f = blockIdx.x;
  const int xcd = f & 7, i = f >> 3;
  const int bh = xcd * 8 + (i >> 3);
  const int qt = i & 7;
  const int b = bh >> 4, h = bh & 15;
  const int tid = threadIdx.x, lane = tid & 63, wid = tid >> 6;
  const int l31 = lane & 31, hi = lane >> 5;
  const int qrow0 = qt * 256 + wid * 32;

  bf16x8 qf[4];
  {
    const u16* qp = Qb + ((size_t)(b * 2048 + qrow0 + l31)) * 1024 + h * 64;
#pragma unroll
    for (int dc = 0; dc < 4; ++dc) qf[dc] = *(const bf16x8*)(qp + dc * 16 + hi * 8);
  }

  const u16* kbase = Kb + ((size_t)(b * 2048)) * 1024 + h * 64;
  const u16* vbase = Vt + ((size_t)(bh * 64)) * 2048;
  const float* mrow = mask + b * 2048;

  const int l31s = tid & 31, his = (tid >> 5) & 1, mid = (tid >> 6) & 3,
            top = (tid >> 8) & 1;
  const int koff = (top * 32 + l31s) * 1024 + (mid * 2 + his) * 8;
  const int voff = (top * 32 + l31s) * 2048 + (mid * 2 + his) * 8;

  f32x16 o0 = {}, o1 = {};
  float l_r = 0.f;

#define STAGE(bufi, tt)                               \
  do {                                                \
    const u16* kb_t = kbase + (size_t)(tt) * 65536;   \
    const u16* vb_t = vbase + (tt) * 64;              \
    gload_lds16(kb_t + koff, &Kl[bufi][tid * 8]);     \
    gload_lds16(vb_t + voff, &Vl[bufi][tid * 8]);     \
  } while (0)

  STAGE(0, 0);

#pragma unroll
  for (int tt = 0; tt < 4; ++tt) {
    const int tile = wid * 4 + tt;
    const unsigned long long bmv = __ballot(mrow[tile * 64 + lane] == 1.0f);
    if (lane == 0) bml[tile] = bmv;
  }
  __syncthreads();

  const unsigned mflags =
      (unsigned)__ballot(lane < 32 && bml[lane] != ~0ull);

  for (int t = 0; t < 32; ++t) {
    const int cur = t & 1;
    if (t + 1 < 32) STAGE(cur ^ 1, t + 1);

    const u16* Kc = Kl[cur];
    const u16* Vc = Vl[cur];

#pragma unroll
    for (int n = 0; n < 2; ++n) {
      f32x16 acc = {};
#pragma unroll
      for (int dc = 0; dc < 4; ++dc) {
        const bf16x8 kf = *(const bf16x8*)&Kc[(n * 4 + dc) * 512 + lane * 8];
        acc = __builtin_amdgcn_mfma_f32_32x32x16_bf16(kf, qf[dc], acc, 0, 0, 0);
      }

#pragma unroll
      for (int reg = 0; reg < 16; ++reg) acc[reg] = exp2_hw(acc[reg]);

      if (mflags & (1u << t)) {
        const unsigned long long bm = bml[t];
#pragma unroll
        for (int reg = 0; reg < 16; ++reg) {
          const int k = n * 32 + (reg & 3) + 8 * (reg >> 2) + 4 * hi;
          if (!((bm >> k) & 1)) acc[reg] = 0.f;
        }
      }

      {
        float s0a = (acc[0] + acc[1]) + (acc[2] + acc[3]);
        float s1a = (acc[4] + acc[5]) + (acc[6] + acc[7]);
        float s2a = (acc[8] + acc[9]) + (acc[10] + acc[11]);
        float s3a = (acc[12] + acc[13]) + (acc[14] + acc[15]);
        l_r += (s0a + s1a) + (s2a + s3a);
      }

      bf16x8 pa0, pa1;
      {
        union { unsigned u[4]; bf16x8 v; } pk;
#pragma unroll
        for (int j = 0; j < 4; ++j) pk.u[j] = cvtpk_bf16(acc[2 * j], acc[2 * j + 1]);
        pa0 = pk.v;
#pragma unroll
        for (int j = 0; j < 4; ++j) pk.u[j] = cvtpk_bf16(acc[8 + 2 * j], acc[9 + 2 * j]);
        pa1 = pk.v;
      }

      {
        const bf16x8 v00 = *(const bf16x8*)&Vc[(0 * 4 + n * 2 + 0) * 512 + lane * 8];
        const bf16x8 v01 = *(const bf16x8*)&Vc[(0 * 4 + n * 2 + 1) * 512 + lane * 8];
        o0 = __builtin_amdgcn_mfma_f32_32x32x16_bf16(pa0, v00, o0, 0, 0, 0);
        o0 = __builtin_amdgcn_mfma_f32_32x32x16_bf16(pa1, v01, o0, 0, 0, 0);
      }
      {
        const bf16x8 v10 = *(const bf16x8*)&Vc[(1 * 4 + n * 2 + 0) * 512 + lane * 8];
        const bf16x8 v11 = *(const bf16x8*)&Vc[(1 * 4 + n * 2 + 1) * 512 + lane * 8];
        o1 = __builtin_amdgcn_mfma_f32_32x32x16_bf16(pa0, v10, o1, 0, 0, 0);
        o1 = __builtin_amdgcn_mfma_f32_32x32x16_bf16(pa1, v11, o1, 0, 0, 0);
      }
    }

    __syncthreads();
  }
#undef STAGE

  const float l_tot = l_r + __shfl_xor(l_r, 32);
  const float linv = 1.0f / l_tot;
  if (!hi) lbuf[wid][l31] = linv;
  __builtin_amdgcn_wave_barrier();
  float lv[16];
#pragma unroll
  for (int reg = 0; reg < 16; ++reg)
    lv[reg] = lbuf[wid][(reg & 3) + 8 * (reg >> 2) + 4 * hi];

  u16* ob = Ob + ((size_t)(b * 2048 + qrow0)) * 1024 + h * 64 + l31;
#pragma unroll
  for (int reg = 0; reg < 16; ++reg) {
    const int q = (reg & 3) + 8 * (reg >> 2) + 4 * hi;
    ob[(size_t)q * 1024] = f2b(o0[reg] * lv[reg]);
    ob[(size_t)q * 1024 + 32] = f2b(o1[reg] * lv[reg]);
  }
}

// ---------------- launch ----------------
extern "C" void kernel_launch(void* const* d_in, const int* in_sizes, int n_in,
                              void* d_out, int out_size, void* d_ws, size_t ws_size,
                              hipStream_t stream) {
  const float* query = (const float*)d_in[0];
  const float* keyin = (const float*)d_in[1];
  const float* maskp = (const float*)d_in[2];
  const float* Wq = (const float*)d_in[3];
  const float* bq = (const float*)d_in[4];
  const float* Wk = (const float*)d_in[5];
  const float* bk = (const float*)d_in[6];
  const float* Wv = (const float*)d_in[7];
  const float* bv = (const float*)d_in[8];
  const float* Wo = (const float*)d_in[9];
  const float* bo = (const float*)d_in[10];

  char* ws = (char*)d_ws;
  const size_t ACT = (size_t)8192 * 1024 * 2;   // 16 MB per bf16 activation buffer
  const size_t WMAT = (size_t)1024 * 1024 * 2;  // 2 MB per bf16 weight
  u16* qbf = (u16*)(ws);
  u16* kbf = (u16*)(ws + ACT);                  // later reused as attn out
  u16* wqb = (u16*)(ws + 2 * ACT);
  u16* wkb = (u16*)(ws + 2 * ACT + WMAT);
  u16* wvb = (u16*)(ws + 2 * ACT + 2 * WMAT);
  u16* wob = (u16*)(ws + 2 * ACT + 3 * WMAT);
  u16* Qb  = (u16*)(ws + 2 * ACT + 4 * WMAT);
  u16* Kb  = (u16*)(ws + 3 * ACT + 4 * WMAT);
  u16* VtDed = (u16*)(ws + 4 * ACT + 4 * WMAT);  // dedicated Vt2 region
  u16* attnb = kbf;

  cvt_all<<<20480, 256, 0, stream>>>(query, keyin, Wq, Wk, Wv, Wo,
                                     qbf, kbf, wqb, wkb, wvb, wob);

  gemm_qkv<<<dim3(64, 24), 256, 0, stream>>>(qbf, kbf, wqb, wkb, wvb,
                                             bq, bk, bv, Qb, Kb, VtDed, 1024);

  flash18<<<512, 512, 0, stream>>>(Qb, Kb, VtDed, maskp, attnb);

  gemm_o<<<dim3(64, 8), 256, 0, stream>>>(attnb, wob, bo, (float*)d_out, 1024);
}

// Round 26
// 169.441 us; speedup vs baseline: 1.1154x; 1.0616x over previous
//
#include <hip/hip_runtime.h>

typedef unsigned short u16;
typedef __attribute__((ext_vector_type(8))) short bf16x8;
typedef __attribute__((ext_vector_type(4))) float f32x4;
typedef __attribute__((ext_vector_type(16))) float f32x16;

#define LOG2E 1.44269504088896f

__device__ inline u16 f2b(float f) {
  union { float f; unsigned u; } x; x.f = f;
  unsigned r = x.u + 0x7fffu + ((x.u >> 16) & 1u);
  return (u16)(r >> 16);
}

__device__ inline void gload_lds16(const void* g, void* l) {
  __builtin_amdgcn_global_load_lds(
      (__attribute__((address_space(1))) void*)(g),
      (__attribute__((address_space(3))) void*)(l), 16, 0, 0);
}

__device__ inline unsigned cvtpk_bf16(float lo, float hi_) {
  unsigned r;
  asm("v_cvt_pk_bf16_f32 %0, %1, %2" : "=v"(r) : "v"(lo), "v"(hi_));
  return r;
}
// exp2 via builtin: emits v_exp_f32 WITH required TRANS-pipe hazard nops.
__device__ inline float exp2_hw(float x) { return __builtin_amdgcn_exp2f(x); }

// ---------------- fused f32 -> bf16 convert (all 6 tensors, one launch) ----------------
__global__ __launch_bounds__(256) void cvt_all(
    const float* __restrict__ q, const float* __restrict__ k,
    const float* __restrict__ wq, const float* __restrict__ wk,
    const float* __restrict__ wv, const float* __restrict__ wo,
    u16* __restrict__ qb, u16* __restrict__ kb,
    u16* __restrict__ wqb, u16* __restrict__ wkb,
    u16* __restrict__ wvb, u16* __restrict__ wob) {
  int b = blockIdx.x;
  const float* in;
  u16* out;
  if (b < 8192) {
    in = q; out = qb;
  } else if (b < 16384) {
    in = k; out = kb; b -= 8192;
  } else {
    const int w = (b - 16384) >> 10;
    b = (b - 16384) & 1023;
    in = (w == 0) ? wq : (w == 1) ? wk : (w == 2) ? wv : wo;
    out = (w == 0) ? wqb : (w == 1) ? wkb : (w == 2) ? wvb : wob;
  }
  const int i = b * 256 + threadIdx.x;
  const float4 v = ((const float4*)in)[i];
  union { u16 s[4]; uint2 u; } o;
  o.s[0] = f2b(v.x); o.s[1] = f2b(v.y); o.s[2] = f2b(v.z); o.s[3] = f2b(v.w);
  ((uint2*)out)[i] = o.u;
}

// ---- BK=64 GEMM, SINGLE-buffered LDS (m97 reference structure: stage ->
// barrier -> compute -> barrier; 32 KB LDS -> 4-5 blocks/CU vs dbuf's 2).
// XOR swizzle unchanged (linear LDS dest, pre-swizzled source ch=(c&7)^(r&7),
// same XOR on read).

// ---------------- O-GEMM ----------------
__global__ __launch_bounds__(256, 4) void gemm_o(
    const u16* __restrict__ A, const u16* __restrict__ W,
    const float* __restrict__ bias, float* __restrict__ Cout,
    int K) {
  __shared__ __align__(16) u16 lA[128 * 64];
  __shared__ __align__(16) u16 lW[128 * 64];
  const int tid = threadIdx.x, lane = tid & 63, wid = tid >> 6;
  const int wr = wid >> 1, wc = wid & 1;
  const int fr = lane & 15, fq = lane >> 4;
  const size_t abase = (size_t)blockIdx.x * 128 * K;
  const size_t wbase = (size_t)blockIdx.y * 128 * K;

  f32x4 acc[4][4];
#pragma unroll
  for (int i = 0; i < 4; ++i)
#pragma unroll
    for (int j = 0; j < 4; ++j) acc[i][j] = (f32x4){0.f, 0.f, 0.f, 0.f};

#define GSTAGE(kt)                                                                \
  do {                                                                            \
    _Pragma("unroll")                                                             \
    for (int is = 0; is < 4; ++is) {                                              \
      const int c = is * 256 + tid;                                               \
      const int r = c >> 3, ch = (c & 7) ^ (r & 7);                               \
      gload_lds16(A + abase + (size_t)r * K + (kt) + ch * 8, lA + c * 8);         \
      gload_lds16(W + wbase + (size_t)r * K + (kt) + ch * 8, lW + c * 8);         \
    }                                                                             \
  } while (0)

  for (int kt = 0; kt < K; kt += 64) {
    GSTAGE(kt);
    __syncthreads();  // staging landed
#pragma unroll
    for (int kk = 0; kk < 2; ++kk) {
      bf16x8 af[4], wf[4];
#pragma unroll
      for (int m = 0; m < 4; ++m) {
        const int row = wr * 64 + m * 16 + fr;
        af[m] = *(const bf16x8*)&lA[row * 64 + (((kk * 4 + fq) ^ (row & 7)) << 3)];
      }
#pragma unroll
      for (int n = 0; n < 4; ++n) {
        const int row = wc * 64 + n * 16 + fr;
        wf[n] = *(const bf16x8*)&lW[row * 64 + (((kk * 4 + fq) ^ (row & 7)) << 3)];
      }
#pragma unroll
      for (int m = 0; m < 4; ++m)
#pragma unroll
        for (int n = 0; n < 4; ++n)
          acc[m][n] = __builtin_amdgcn_mfma_f32_16x16x32_bf16(af[m], wf[n], acc[m][n], 0, 0, 0);
    }
    __syncthreads();  // all reads done before next stage overwrites
  }
#undef GSTAGE

  const int row0 = blockIdx.x * 128 + wr * 64 + fq * 4;
  const int col0 = blockIdx.y * 128 + wc * 64 + fr;
#pragma unroll
  for (int n = 0; n < 4; ++n) {
    const int col = col0 + n * 16;
    const float bb = bias[col];
#pragma unroll
    for (int m = 0; m < 4; ++m) {
#pragma unroll
      for (int r = 0; r < 4; ++r) {
        const int row = row0 + m * 16 + r;
        Cout[(size_t)row * 1024 + col] = acc[m][n][r] + bb;
      }
    }
  }
}

// ---------------- fused Q+K+V GEMM ----------------
// grid (64,24): y<8 -> Q (alpha=0.125*LOG2E, from qA); 8<=y<16 -> K (from kA);
// y>=16 -> V (from kA, fused Vt2-permute epilogue).
__global__ __launch_bounds__(256, 4) void gemm_qkv(
    const u16* __restrict__ qA, const u16* __restrict__ kA,
    const u16* __restrict__ Wq, const u16* __restrict__ Wk,
    const u16* __restrict__ Wv, const float* __restrict__ bq,
    const float* __restrict__ bk, const float* __restrict__ bv,
    u16* __restrict__ Qout, u16* __restrict__ Kout,
    u16* __restrict__ Vtout, int K) {
  __shared__ __align__(16) u16 lA[128 * 64];
  __shared__ __align__(16) u16 lW[128 * 64];
  const int tid = threadIdx.x, lane = tid & 63, wid = tid >> 6;
  const int wr = wid >> 1, wc = wid & 1;
  const int fr = lane & 15, fq = lane >> 4;
  const int path = blockIdx.y >> 3, ny = blockIdx.y & 7;
  const u16* A = (path == 0) ? qA : kA;
  const u16* W = (path == 0) ? Wq : (path == 1) ? Wk : Wv;
  const float* bias = (path == 0) ? bq : (path == 1) ? bk : bv;
  const size_t abase = (size_t)blockIdx.x * 128 * K;
  const size_t wbase = (size_t)ny * 128 * K;

  f32x4 acc[4][4];
#pragma unroll
  for (int i = 0; i < 4; ++i)
#pragma unroll
    for (int j = 0; j < 4; ++j) acc[i][j] = (f32x4){0.f, 0.f, 0.f, 0.f};

#define GSTAGE(kt)                                                                \
  do {                                                                            \
    _Pragma("unroll")                                                             \
    for (int is = 0; is < 4; ++is) {                                              \
      const int c = is * 256 + tid;                                               \
      const int r = c >> 3, ch = (c & 7) ^ (r & 7);                               \
      gload_lds16(A + abase + (size_t)r * K + (kt) + ch * 8, lA + c * 8);         \
      gload_lds16(W + wbase + (size_t)r * K + (kt) + ch * 8, lW + c * 8);         \
    }                                                                             \
  } while (0)

  for (int kt = 0; kt < K; kt += 64) {
    GSTAGE(kt);
    __syncthreads();  // staging landed
#pragma unroll
    for (int kk = 0; kk < 2; ++kk) {
      bf16x8 af[4], wf[4];
#pragma unroll
      for (int m = 0; m < 4; ++m) {
        const int row = wr * 64 + m * 16 + fr;
        af[m] = *(const bf16x8*)&lA[row * 64 + (((kk * 4 + fq) ^ (row & 7)) << 3)];
      }
#pragma unroll
      for (int n = 0; n < 4; ++n) {
        const int row = wc * 64 + n * 16 + fr;
        wf[n] = *(const bf16x8*)&lW[row * 64 + (((kk * 4 + fq) ^ (row & 7)) << 3)];
      }
#pragma unroll
      for (int m = 0; m < 4; ++m)
#pragma unroll
        for (int n = 0; n < 4; ++n)
          acc[m][n] = __builtin_amdgcn_mfma_f32_16x16x32_bf16(af[m], wf[n], acc[m][n], 0, 0, 0);
    }
    __syncthreads();  // all reads done before next stage overwrites
  }
#undef GSTAGE

  if (path == 2) {
    // fused V epilogue: write bf16 directly in Vt2-permuted layout
    const int bI = blockIdx.x >> 4;
    const int srow0 = ((blockIdx.x * 128) & 2047) + wr * 64 + fq * 4;
    const int col0 = ny * 128 + wc * 64 + fr;
#pragma unroll
    for (int n = 0; n < 4; ++n) {
      const int col = col0 + n * 16;
      const float bb = bias[col];
      const int h = col >> 6, dl = col & 63;
      u16* vrow = Vtout + ((size_t)((bI * 16 + h) * 64 + dl)) * 2048;
#pragma unroll
      for (int m = 0; m < 4; ++m) {
        const int s = srow0 + m * 16;
        const int x = s & 15;
        const int pos = (((s & 63) >> 4) * 2 + ((x >> 2) & 1)) * 8 + ((x & 3) | ((x & 8) >> 1));
        union { u16 s4[4]; uint2 u; } w;
#pragma unroll
        for (int r = 0; r < 4; ++r) w.s4[r] = f2b(acc[m][n][r] + bb);
        *(uint2*)&vrow[(s >> 6) * 64 + pos] = w.u;
      }
    }
  } else {
    const float alpha = (path == 0) ? 0.125f * LOG2E : 1.0f;
    u16* Cout = (path == 0) ? Qout : Kout;
    const int row0 = blockIdx.x * 128 + wr * 64 + fq * 4;
    const int col0 = ny * 128 + wc * 64 + fr;
#pragma unroll
    for (int n = 0; n < 4; ++n) {
      const int col = col0 + n * 16;
      const float bb = bias[col];
#pragma unroll
      for (int m = 0; m < 4; ++m) {
#pragma unroll
        for (int r = 0; r < 4; ++r) {
          const int row = row0 + m * 16 + r;
          Cout[(size_t)row * 1024 + col] = f2b((acc[m][n][r] + bb) * alpha);
        }
      }
    }
  }
}

// ---------------- flash attention fwd (v18: round-25 proven, unchanged) ----------------
__global__ __launch_bounds__(512, 3) void flash18(
    const u16* __restrict__ Qb, const u16* __restrict__ Kb,
    const u16* __restrict__ Vt, const float* __restrict__ mask,
    u16* __restrict__ Ob) {
  __shared__ __align__(16) u16 Kl[2][4096];
  __shared__ __align__(16) u16 Vl[2][4096];
  __shared__ unsigned long long bml[32];
  __shared__ float lbuf[8][32];

  const int f = blockIdx.x;
  const int xcd = f & 7, i = f >> 3;
  const int bh = xcd * 8 + (i >> 3);
  const int qt = i & 7;
  const int b = bh >> 4, h = bh & 15;
  const int tid = threadIdx.x, lane = tid & 63, wid = tid >> 6;
  const int l31 = lane & 31, hi = lane >> 5;
  const int qrow0 = qt * 256 + wid * 32;

  bf16x8 qf[4];
  {
    const u16* qp = Qb + ((size_t)(b * 2048 + qrow0 + l31)) * 1024 + h * 64;
#pragma unroll
    for (int dc = 0; dc < 4; ++dc) qf[dc] = *(const bf16x8*)(qp + dc * 16 + hi * 8);
  }

  const u16* kbase = Kb + ((size_t)(b * 2048)) * 1024 + h * 64;
  const u16* vbase = Vt + ((size_t)(bh * 64)) * 2048;
  const float* mrow = mask + b * 2048;

  const int l31s = tid & 31, his = (tid >> 5) & 1, mid = (tid >> 6) & 3,
            top = (tid >> 8) & 1;
  const int koff = (top * 32 + l31s) * 1024 + (mid * 2 + his) * 8;
  const int voff = (top * 32 + l31s) * 2048 + (mid * 2 + his) * 8;

  f32x16 o0 = {}, o1 = {};
  float l_r = 0.f;

#define STAGE(bufi, tt)                               \
  do {                                                \
    const u16* kb_t = kbase + (size_t)(tt) * 65536;   \
    const u16* vb_t = vbase + (tt) * 64;              \
    gload_lds16(kb_t + koff, &Kl[bufi][tid * 8]);     \
    gload_lds16(vb_t + voff, &Vl[bufi][tid * 8]);     \
  } while (0)

  STAGE(0, 0);

#pragma unroll
  for (int tt = 0; tt < 4; ++tt) {
    const int tile = wid * 4 + tt;
    const unsigned long long bmv = __ballot(mrow[tile * 64 + lane] == 1.0f);
    if (lane == 0) bml[tile] = bmv;
  }
  __syncthreads();

  const unsigned mflags =
      (unsigned)__ballot(lane < 32 && bml[lane] != ~0ull);

  for (int t = 0; t < 32; ++t) {
    const int cur = t & 1;
    if (t + 1 < 32) STAGE(cur ^ 1, t + 1);

    const u16* Kc = Kl[cur];
    const u16* Vc = Vl[cur];

#pragma unroll
    for (int n = 0; n < 2; ++n) {
      f32x16 acc = {};
#pragma unroll
      for (int dc = 0; dc < 4; ++dc) {
        const bf16x8 kf = *(const bf16x8*)&Kc[(n * 4 + dc) * 512 + lane * 8];
        acc = __builtin_amdgcn_mfma_f32_32x32x16_bf16(kf, qf[dc], acc, 0, 0, 0);
      }

#pragma unroll
      for (int reg = 0; reg < 16; ++reg) acc[reg] = exp2_hw(acc[reg]);

      if (mflags & (1u << t)) {
        const unsigned long long bm = bml[t];
#pragma unroll
        for (int reg = 0; reg < 16; ++reg) {
          const int k = n * 32 + (reg & 3) + 8 * (reg >> 2) + 4 * hi;
          if (!((bm >> k) & 1)) acc[reg] = 0.f;
        }
      }

      {
        float s0a = (acc[0] + acc[1]) + (acc[2] + acc[3]);
        float s1a = (acc[4] + acc[5]) + (acc[6] + acc[7]);
        float s2a = (acc[8] + acc[9]) + (acc[10] + acc[11]);
        float s3a = (acc[12] + acc[13]) + (acc[14] + acc[15]);
        l_r += (s0a + s1a) + (s2a + s3a);
      }

      bf16x8 pa0, pa1;
      {
        union { unsigned u[4]; bf16x8 v; } pk;
#pragma unroll
        for (int j = 0; j < 4; ++j) pk.u[j] = cvtpk_bf16(acc[2 * j], acc[2 * j + 1]);
        pa0 = pk.v;
#pragma unroll
        for (int j = 0; j < 4; ++j) pk.u[j] = cvtpk_bf16(acc[8 + 2 * j], acc[9 + 2 * j]);
        pa1 = pk.v;
      }

      {
        const bf16x8 v00 = *(const bf16x8*)&Vc[(0 * 4 + n * 2 + 0) * 512 + lane * 8];
        const bf16x8 v01 = *(const bf16x8*)&Vc[(0 * 4 + n * 2 + 1) * 512 + lane * 8];
        o0 = __builtin_amdgcn_mfma_f32_32x32x16_bf16(pa0, v00, o0, 0, 0, 0);
        o0 = __builtin_amdgcn_mfma_f32_32x32x16_bf16(pa1, v01, o0, 0, 0, 0);
      }
      {
        const bf16x8 v10 = *(const bf16x8*)&Vc[(1 * 4 + n * 2 + 0) * 512 + lane * 8];
        const bf16x8 v11 = *(const bf16x8*)&Vc[(1 * 4 + n * 2 + 1) * 512 + lane * 8];
        o1 = __builtin_amdgcn_mfma_f32_32x32x16_bf16(pa0, v10, o1, 0, 0, 0);
        o1 = __builtin_amdgcn_mfma_f32_32x32x16_bf16(pa1, v11, o1, 0, 0, 0);
      }
    }

    __syncthreads();
  }
#undef STAGE

  const float l_tot = l_r + __shfl_xor(l_r, 32);
  const float linv = 1.0f / l_tot;
  if (!hi) lbuf[wid][l31] = linv;
  __builtin_amdgcn_wave_barrier();
  float lv[16];
#pragma unroll
  for (int reg = 0; reg < 16; ++reg)
    lv[reg] = lbuf[wid][(reg & 3) + 8 * (reg >> 2) + 4 * hi];

  u16* ob = Ob + ((size_t)(b * 2048 + qrow0)) * 1024 + h * 64 + l31;
#pragma unroll
  for (int reg = 0; reg < 16; ++reg) {
    const int q = (reg & 3) + 8 * (reg >> 2) + 4 * hi;
    ob[(size_t)q * 1024] = f2b(o0[reg] * lv[reg]);
    ob[(size_t)q * 1024 + 32] = f2b(o1[reg] * lv[reg]);
  }
}

// ---------------- launch ----------------
extern "C" void kernel_launch(void* const* d_in, const int* in_sizes, int n_in,
                              void* d_out, int out_size, void* d_ws, size_t ws_size,
                              hipStream_t stream) {
  const float* query = (const float*)d_in[0];
  const float* keyin = (const float*)d_in[1];
  const float* maskp = (const float*)d_in[2];
  const float* Wq = (const float*)d_in[3];
  const float* bq = (const float*)d_in[4];
  const float* Wk = (const float*)d_in[5];
  const float* bk = (const float*)d_in[6];
  const float* Wv = (const float*)d_in[7];
  const float* bv = (const float*)d_in[8];
  const float* Wo = (const float*)d_in[9];
  const float* bo = (const float*)d_in[10];

  char* ws = (char*)d_ws;
  const size_t ACT = (size_t)8192 * 1024 * 2;   // 16 MB per bf16 activation buffer
  const size_t WMAT = (size_t)1024 * 1024 * 2;  // 2 MB per bf16 weight
  u16* qbf = (u16*)(ws);
  u16* kbf = (u16*)(ws + ACT);                  // later reused as attn out
  u16* wqb = (u16*)(ws + 2 * ACT);
  u16* wkb = (u16*)(ws + 2 * ACT + WMAT);
  u16* wvb = (u16*)(ws + 2 * ACT + 2 * WMAT);
  u16* wob = (u16*)(ws + 2 * ACT + 3 * WMAT);
  u16* Qb  = (u16*)(ws + 2 * ACT + 4 * WMAT);
  u16* Kb  = (u16*)(ws + 3 * ACT + 4 * WMAT);
  u16* VtDed = (u16*)(ws + 4 * ACT + 4 * WMAT);  // dedicated Vt2 region
  u16* attnb = kbf;

  cvt_all<<<20480, 256, 0, stream>>>(query, keyin, Wq, Wk, Wv, Wo,
                                     qbf, kbf, wqb, wkb, wvb, wob);

  gemm_qkv<<<dim3(64, 24), 256, 0, stream>>>(qbf, kbf, wqb, wkb, wvb,
                                             bq, bk, bv, Qb, Kb, VtDed, 1024);

  flash18<<<512, 512, 0, stream>>>(Qb, Kb, VtDed, maskp, attnb);

  gemm_o<<<dim3(64, 8), 256, 0, stream>>>(attnb, wob, bo, (float*)d_out, 1024);
}